// Round 5
// baseline (710.421 us; speedup 1.0000x reference)
//
#include <hip/hip_runtime.h>
#include <hip/hip_bf16.h>
#include <math.h>

// ---------------------------------------------------------------------------
// SelfAttn2d: out = x + gamma * (V @ softmax(Q K^T / sqrt(32))^T)
// B=4, C=256, N=4096, D=32.
// Round 5: R4 with the __syncwavefront -> split-region __syncthreads fix.
// 8-wave attn, 32 e-rows/wave (acc=32 VGPR, no spill), n-step 128.
// Fused MFMA projection kernel (v + q + k in one launch).
// ---------------------------------------------------------------------------

#define NPOS 4096
#define PSTR 136   // P row stride (bf16): 272B = 17*16B -> aligned b128, odd word stride
#define XSTR 264   // XT row stride (bf16): 528B = 33*16B -> aligned b128

typedef __bf16 bf16x8 __attribute__((ext_vector_type(8)));
typedef float  f32x16 __attribute__((ext_vector_type(16)));

static __device__ inline unsigned int pk2(float a, float b) {
    union { __hip_bfloat16 h[2]; unsigned int u; } x;
    x.h[0] = __float2bfloat16(a);
    x.h[1] = __float2bfloat16(b);
    return x.u;
}
static __device__ inline bf16x8 cvt8(float4 a, float4 b) {
    union { bf16x8 v; unsigned int u[4]; } t;
    t.u[0] = pk2(a.x, a.y); t.u[1] = pk2(a.z, a.w);
    t.u[2] = pk2(b.x, b.y); t.u[3] = pk2(b.z, b.w);
    return t.v;
}

// ---------------------------------------------------------------------------
// sigma_all: block 0 -> sigma(wq), 1 -> sigma(wk), 2 -> sigma(wv). 512 thr.
// ---------------------------------------------------------------------------
__global__ __launch_bounds__(512) void sigma_all(const float* __restrict__ wq,
                                                 const float* __restrict__ wk,
                                                 const float* __restrict__ wv,
                                                 float* __restrict__ scal) {
    __shared__ __align__(16) __hip_bfloat16 Wsh[256 * XSTR];
    __shared__ float red[512];
    __shared__ float trsh;
    __shared__ float xv[256];

    int t = threadIdx.x;

    if (blockIdx.x < 2) {
        const float* w = (blockIdx.x == 0) ? wq : wk;
        float* F  = (float*)Wsh;
        float* Ws = F;                 // [32][257]
        float* G  = F + 32 * 257;
        float* A  = G + 32 * 33;
        float* Bt = A + 32 * 33;
        float* xq = Bt + 32 * 33;
        float* yq = xq + 32;

        if (t < 256) {
            for (int i = 0; i < 32; i++) {
                int idx = t + 256 * i;
                Ws[(idx >> 8) * 257 + (idx & 255)] = w[idx];
            }
        }
        __syncthreads();
        if (t < 256) {
            for (int i = 0; i < 4; i++) {
                int id = t + 256 * i;
                int r = id >> 5, cc = id & 31;
                float s = 0.f;
                for (int c = 0; c < 256; c++) s += Ws[r * 257 + c] * Ws[cc * 257 + c];
                G[r * 33 + cc] = s;
                A[r * 33 + cc] = s;
            }
        }
        __syncthreads();
        for (int sq = 0; sq < 8; sq++) {
            if (t == 0) {
                float tr = 0.f;
                for (int i = 0; i < 32; i++) tr += A[i * 33 + i];
                trsh = 1.0f / tr;
            }
            __syncthreads();
            float invt = trsh;
            if (t < 256) {
                for (int i = 0; i < 4; i++) {
                    int id = t + 256 * i;
                    int r = id >> 5, cc = id & 31;
                    float s = 0.f;
                    #pragma unroll
                    for (int k2 = 0; k2 < 32; k2++) s += A[r * 33 + k2] * A[cc * 33 + k2];
                    Bt[r * 33 + cc] = s * invt * invt;
                }
            }
            __syncthreads();
            if (t < 256) {
                for (int i = 0; i < 4; i++) {
                    int id = t + 256 * i;
                    A[(id >> 5) * 33 + (id & 31)] = Bt[(id >> 5) * 33 + (id & 31)];
                }
            }
            __syncthreads();
        }
        if (t < 32) xq[t] = 1.0f + 0.01f * t;
        __syncthreads();
        for (int it = 0; it < 4; it++) {
            if (t < 32) {
                float y = 0.f;
                #pragma unroll
                for (int j = 0; j < 32; j++) y += A[t * 33 + j] * xq[j];
                yq[t] = y;
            }
            __syncthreads();
            if (t < 32) {
                float ss = 0.f;
                #pragma unroll
                for (int j = 0; j < 32; j++) ss += yq[j] * yq[j];
                xq[t] = yq[t] * rsqrtf(ss);
            }
            __syncthreads();
        }
        if (t == 0) {
            float lam = 0.f;
            for (int i = 0; i < 32; i++) {
                float y = 0.f;
                for (int j = 0; j < 32; j++) y += G[i * 33 + j] * xq[j];
                lam += xq[i] * y;
            }
            scal[blockIdx.x] = rsqrtf(lam);
        }
        return;
    }

    // v path: 256x256 Gram^64 chain on MFMA in LDS
    int wave = t >> 6, lane = t & 63, lo = lane & 31, hi = lane >> 5;
    int p = wave >> 1;
    int q = wave & 1;

    for (int i = 0; i < 128; i++) {
        int idx = t + 512 * i;
        Wsh[(idx >> 8) * XSTR + (idx & 255)] = __float2bfloat16(wv[idx]);
    }
    __syncthreads();

    for (int round = 0; round < 7; round++) {
        f32x16 c[2][4];
        #pragma unroll
        for (int mt = 0; mt < 2; mt++)
            #pragma unroll
            for (int j = 0; j < 4; j++)
                #pragma unroll
                for (int r = 0; r < 16; r++) c[mt][j][r] = 0.f;

        for (int kc = 0; kc < 16; kc++) {
            bf16x8 af[2], bfj[4];
            #pragma unroll
            for (int mt = 0; mt < 2; mt++)
                af[mt] = *(const bf16x8*)&Wsh[((2 * p + mt) * 32 + lo) * XSTR + kc * 16 + hi * 8];
            #pragma unroll
            for (int j = 0; j < 4; j++)
                bfj[j] = *(const bf16x8*)&Wsh[((4 * q + j) * 32 + lo) * XSTR + kc * 16 + hi * 8];
            #pragma unroll
            for (int mt = 0; mt < 2; mt++)
                #pragma unroll
                for (int j = 0; j < 4; j++)
                    c[mt][j] = __builtin_amdgcn_mfma_f32_32x32x16_bf16(af[mt], bfj[j], c[mt][j], 0, 0, 0);
        }

        float dsum = 0.f;
        #pragma unroll
        for (int mt = 0; mt < 2; mt++) {
            int Tm = 2 * p + mt;
            if ((Tm >> 2) == q) {
                int j = Tm - 4 * q;
                #pragma unroll
                for (int r = 0; r < 16; r++) {
                    int row = (r & 3) + 8 * (r >> 2) + 4 * hi;
                    if (row == lo) dsum += c[mt][j][r];
                }
            }
        }
        red[t] = dsum;
        __syncthreads();
        for (int s2 = 256; s2 > 0; s2 >>= 1) {
            if (t < s2) red[t] += red[t + s2];
            __syncthreads();
        }
        float invt = 1.0f / red[0];
        __syncthreads();

        #pragma unroll
        for (int mt = 0; mt < 2; mt++)
            #pragma unroll
            for (int j = 0; j < 4; j++)
                #pragma unroll
                for (int r = 0; r < 16; r++) {
                    int row = (2 * p + mt) * 32 + (r & 3) + 8 * (r >> 2) + 4 * hi;
                    int col = (4 * q + j) * 32 + lo;
                    Wsh[row * XSTR + col] = __float2bfloat16(c[mt][j][r] * invt);
                }
        __syncthreads();
    }

    if (t < 256) xv[t] = 1.0f + 0.01f * t;
    __syncthreads();
    for (int it = 0; it < 8; it++) {
        float y = 0.f;
        if (t < 256) {
            for (int ch = 0; ch < 32; ch++) {
                bf16x8 a = *(const bf16x8*)&Wsh[t * XSTR + ch * 8];
                #pragma unroll
                for (int e = 0; e < 8; e++) y += (float)a[e] * xv[ch * 8 + e];
            }
        }
        red[t] = (t < 256) ? y * y : 0.f;
        __syncthreads();
        for (int s2 = 256; s2 > 0; s2 >>= 1) {
            if (t < s2) red[t] += red[t + s2];
            __syncthreads();
        }
        if (t == 0) trsh = rsqrtf(red[0]);
        __syncthreads();
        if (t < 256) xv[t] = y * trsh;
        __syncthreads();
    }

    float z = 0.f;
    if (t < 256) {
        for (int i = 0; i < 256; i++) z += wv[i * 256 + t] * xv[i];
    }
    red[t] = (t < 256) ? z * z : 0.f;
    __syncthreads();
    for (int s2 = 256; s2 > 0; s2 >>= 1) {
        if (t < s2) red[t] += red[t + s2];
        __syncthreads();
    }
    if (t == 0) scal[2] = rsqrtf(red[0]);
}

// ---------------------------------------------------------------------------
// proj: fused MFMA projection. Grid (64 n-tiles, 4 b), 512 thr (8 waves).
// Stage X^T tile [64 n][256 c] bf16 in LDS. Wave w: v j-tile w (e=32w..32w+32)
// x 2 i-tiles; waves 0..3 additionally one q/k fragment each.
// Outputs: v[b][e][n] (packed uint2 stores), qT/kT[b][n][32] via LDS transpose.
// ---------------------------------------------------------------------------
__global__ __launch_bounds__(512) void proj(const float* __restrict__ x,
                                            const float* __restrict__ wq,
                                            const float* __restrict__ wk,
                                            const float* __restrict__ wv,
                                            __hip_bfloat16* __restrict__ qT,
                                            __hip_bfloat16* __restrict__ kT,
                                            __hip_bfloat16* __restrict__ v) {
    __shared__ __align__(16) __hip_bfloat16 XT[64 * XSTR];    // 33.8 KB
    __shared__ __align__(16) __hip_bfloat16 Tq[4][32 * 40];   // 10 KB transpose buf

    int t = threadIdx.x;
    int wave = t >> 6, lane = t & 63, lo = lane & 31, hi = lane >> 5;
    int n0 = blockIdx.x * 64;
    int b = blockIdx.y;
    const float* xb = x + ((size_t)b << 20);

    // stage: XT[n][c] = bf16(x[c][n0+n]); 8 c-groups of 32
    {
        int nl = t & 63, cg = t >> 6;
        #pragma unroll 8
        for (int i = 0; i < 32; i++) {
            int c = cg * 32 + i;
            XT[nl * XSTR + c] = __float2bfloat16(xb[(size_t)c * NPOS + n0 + nl]);
        }
    }
    __syncthreads();

    f32x16 accv[2], accq;
    #pragma unroll
    for (int it = 0; it < 2; it++)
        #pragma unroll
        for (int r = 0; r < 16; r++) accv[it][r] = 0.f;
    #pragma unroll
    for (int r = 0; r < 16; r++) accq[r] = 0.f;

    const float* wvrow = wv + (size_t)(wave * 32 + lo) * 256 + hi * 8;
    const float* wqkrow = ((wave < 2) ? wq : wk) + (size_t)lo * 256 + hi * 8;
    int qk_it = wave & 1;  // i-tile for the qk fragment (waves 0..3)

    for (int kc = 0; kc < 16; kc++) {
        bf16x8 af0 = *(const bf16x8*)&XT[lo * XSTR + kc * 16 + hi * 8];
        bf16x8 af1 = *(const bf16x8*)&XT[(32 + lo) * XSTR + kc * 16 + hi * 8];
        float4 wa = *(const float4*)(wvrow + kc * 16);
        float4 wb = *(const float4*)(wvrow + kc * 16 + 4);
        bf16x8 bfv = cvt8(wa, wb);
        accv[0] = __builtin_amdgcn_mfma_f32_32x32x16_bf16(af0, bfv, accv[0], 0, 0, 0);
        accv[1] = __builtin_amdgcn_mfma_f32_32x32x16_bf16(af1, bfv, accv[1], 0, 0, 0);
        if (wave < 4) {
            float4 qa = *(const float4*)(wqkrow + kc * 16);
            float4 qb = *(const float4*)(wqkrow + kc * 16 + 4);
            bf16x8 bfq = cvt8(qa, qb);
            accq = __builtin_amdgcn_mfma_f32_32x32x16_bf16(qk_it ? af1 : af0, bfq, accq, 0, 0, 0);
        }
    }

    // ---- v epilogue: C col = e-local(lo), row = n pattern. uint2 packed stores.
    __hip_bfloat16* vbb = v + ((size_t)b << 20) + (size_t)(wave * 32 + lo) * NPOS + n0;
    #pragma unroll
    for (int it = 0; it < 2; it++)
        #pragma unroll
        for (int g = 0; g < 4; g++) {
            uint2 pk;
            pk.x = pk2(accv[it][4 * g + 0], accv[it][4 * g + 1]);
            pk.y = pk2(accv[it][4 * g + 2], accv[it][4 * g + 3]);
            *(uint2*)(vbb + it * 32 + 8 * g + 4 * hi) = pk;
        }

    // ---- qk epilogue: transpose 32n x 32d through LDS, coalesced b128 out.
    if (wave < 4) {
        __hip_bfloat16* T = Tq[wave];
        #pragma unroll
        for (int r = 0; r < 16; r++) {
            int n = (r & 3) + 8 * (r >> 2) + 4 * hi;
            T[n * 40 + lo] = __float2bfloat16(accq[r]);
        }
    }
    __syncthreads();  // uniform barrier: transpose buffers visible
    if (wave < 4) {
        __hip_bfloat16* T = Tq[wave];
        __hip_bfloat16* dst = ((wave < 2) ? qT : kT) + ((size_t)b << 17)
                              + (size_t)(n0 + qk_it * 32) * 32;
        #pragma unroll
        for (int p = 0; p < 2; p++) {
            int idx = p * 64 + lane;
            int n = idx >> 2, quad = idx & 3;
            bf16x8 row = *(const bf16x8*)&T[n * 40 + quad * 8];
            *(bf16x8*)(dst + (size_t)n * 32 + quad * 8) = row;
        }
    }
}

// ---------------------------------------------------------------------------
// MFMA flash attention. 512 thr (8 waves), grid 256 (64 m-tiles x 4 b).
// n-step 128. Wave w: S^T quadrant (mtile=w>>2, ntile=w&3) -> P[m][n] LDS;
// PV: e-rows [32w,32w+32), 8x(V global b128 + 2 P b128 + 2 MFMA).
// acc = 32 VGPR/wave; vf single-buffer [8]; kf double-buffered. No merge buf.
// No max-subtraction (spectral norm bounds logits << fp32 exp range).
// ---------------------------------------------------------------------------
__global__ __launch_bounds__(512) void attn_mfma(const float* __restrict__ x,
                                                 const __hip_bfloat16* __restrict__ qT,
                                                 const __hip_bfloat16* __restrict__ kT,
                                                 const __hip_bfloat16* __restrict__ v,
                                                 const float* __restrict__ scal,
                                                 const float* __restrict__ gam,
                                                 float* __restrict__ out) {
    __shared__ __align__(16) __hip_bfloat16 Plds[64 * PSTR];  // 17.4 KB
    __shared__ float Lpart[8][32];

    int t = threadIdx.x;
    int wave = t >> 6, lane = t & 63;
    int lo = lane & 31, hi = lane >> 5;

    // XCD swizzle: batch pinned to XCD pair
    int blk = blockIdx.x;
    int x8 = blk & 7;
    int b = x8 >> 1;
    int m0 = (((x8 & 1) << 5) + (blk >> 3)) << 6;

    const __hip_bfloat16* qTb = qT + ((size_t)b << 17);
    const __hip_bfloat16* kTb = kT + ((size_t)b << 17);
    const __hip_bfloat16* vb  = v  + ((size_t)b << 20);

    int mtile = wave >> 2, ntile = wave & 3;
    float qkscale = scal[0] * scal[1] * 0.17677669529663687f;

    // persistent Q B-frag (this wave's m-tile)
    const __hip_bfloat16* qrow = qTb + (size_t)(m0 + mtile * 32 + lo) * 32 + hi * 8;
    bf16x8 qf0 = *(const bf16x8*)(qrow);
    bf16x8 qf1 = *(const bf16x8*)(qrow + 16);

    const __hip_bfloat16* kaddr = kTb + (size_t)(ntile * 32 + lo) * 32 + hi * 8;
    const __hip_bfloat16* vaddr = vb + (size_t)(wave * 32 + lo) * NPOS + hi * 8;

    f32x16 acc[2];
    #pragma unroll
    for (int mt = 0; mt < 2; mt++)
        #pragma unroll
        for (int r = 0; r < 16; r++) acc[mt][r] = 0.f;
    float l_acc = 0.f;

    bf16x8 kf[2][2];
    kf[0][0] = *(const bf16x8*)(kaddr);
    kf[0][1] = *(const bf16x8*)(kaddr + 16);

    for (int s = 0; s < 32; s++) {
        int cur = s & 1, nxt = cur ^ 1;
        int n0 = 128 * s;

        // S^T = K x Q (rows n, cols m)
        f32x16 sv;
        #pragma unroll
        for (int r = 0; r < 16; r++) sv[r] = 0.f;
        sv = __builtin_amdgcn_mfma_f32_32x32x16_bf16(kf[cur][0], qf0, sv, 0, 0, 0);
        sv = __builtin_amdgcn_mfma_f32_32x32x16_bf16(kf[cur][1], qf1, sv, 0, 0, 0);

        // prefetch next K frag
        if (s < 31) {
            const __hip_bfloat16* ka = kaddr + (size_t)(n0 + 128) * 32;
            kf[nxt][0] = *(const bf16x8*)(ka);
            kf[nxt][1] = *(const bf16x8*)(ka + 16);
        }
        // preload this step's V frags (latency hides under exp+barriers)
        bf16x8 vf[8];
        #pragma unroll
        for (int kc = 0; kc < 8; kc++)
            vf[kc] = *(const bf16x8*)(vaddr + n0 + kc * 16);

        __syncthreads();  // prior PV reads of Plds done
        {
            int mrow = mtile * 32 + lo;
            #pragma unroll
            for (int g = 0; g < 4; g++) {
                float p0 = __expf(sv[4 * g + 0] * qkscale);
                float p1 = __expf(sv[4 * g + 1] * qkscale);
                float p2 = __expf(sv[4 * g + 2] * qkscale);
                float p3 = __expf(sv[4 * g + 3] * qkscale);
                l_acc += (p0 + p1) + (p2 + p3);
                uint2 pk;
                pk.x = pk2(p0, p1);
                pk.y = pk2(p2, p3);
                *(uint2*)(&Plds[mrow * PSTR + ntile * 32 + 8 * g + 4 * hi]) = pk;
            }
        }
        __syncthreads();  // P ready

        // PV: D[e][m] += V x P
        #pragma unroll
        for (int kc = 0; kc < 8; kc++) {
            bf16x8 pf0 = *(const bf16x8*)(&Plds[lo * PSTR + kc * 16 + hi * 8]);
            bf16x8 pf1 = *(const bf16x8*)(&Plds[(32 + lo) * PSTR + kc * 16 + hi * 8]);
            acc[0] = __builtin_amdgcn_mfma_f32_32x32x16_bf16(vf[kc], pf0, acc[0], 0, 0, 0);
            acc[1] = __builtin_amdgcn_mfma_f32_32x32x16_bf16(vf[kc], pf1, acc[1], 0, 0, 0);
        }
    }

    // L partials: lane^32 holds same m, other n-rows of the quadrant
    float lsum = l_acc + __shfl_xor(l_acc, 32, 64);
    if (lane < 32) Lpart[wave][lane] = lsum;
    __syncthreads();

    // epilogue: out = x + gamma*sig_v^-1 * acc / L
    float gs = gam[0] * scal[2];
    const float* xb = x + ((size_t)b << 20);
    float* ob = out + ((size_t)b << 20);
    #pragma unroll
    for (int mt = 0; mt < 2; mt++) {
        float L = Lpart[4 * mt][lo] + Lpart[4 * mt + 1][lo] +
                  Lpart[4 * mt + 2][lo] + Lpart[4 * mt + 3][lo];
        float f = gs / L;
        int m = m0 + mt * 32 + lo;
        #pragma unroll
        for (int r = 0; r < 16; r++) {
            int e = wave * 32 + (r & 3) + 8 * (r >> 2) + 4 * hi;
            size_t idx = (size_t)e * NPOS + m;
            ob[idx] = xb[idx] + f * acc[mt][r];
        }
    }
}

// ---------------------------------------------------------------------------
extern "C" void kernel_launch(void* const* d_in, const int* in_sizes, int n_in,
                              void* d_out, int out_size, void* d_ws, size_t ws_size,
                              hipStream_t stream) {
    const float* x     = (const float*)d_in[0];
    const float* wq    = (const float*)d_in[1];
    const float* wk    = (const float*)d_in[2];
    const float* wv    = (const float*)d_in[3];
    const float* gamma = (const float*)d_in[4];
    float* out = (float*)d_out;

    char* wsb = (char*)d_ws;
    float* scal = (float*)wsb;                          // [0..63]
    __hip_bfloat16* qT = (__hip_bfloat16*)(wsb + 256);
    __hip_bfloat16* kT = qT + (size_t)4 * NPOS * 32;
    __hip_bfloat16* vp = kT + (size_t)4 * NPOS * 32;    // 4*256*4096 bf16

    proj<<<dim3(64, 4), 512, 0, stream>>>(x, wq, wk, wv, qT, kT, vp);
    sigma_all<<<3, 512, 0, stream>>>(wq, wk, wv, scal);
    attn_mfma<<<256, 512, 0, stream>>>(x, qT, kT, vp, scal, gamma, out);
}